// Round 1
// baseline (523.925 us; speedup 1.0000x reference)
//
#include <hip/hip_runtime.h>
#include <hip/hip_bf16.h>

#define LSTM_T 512
#define LSTM_CT 16
#define LSTM_NC (LSTM_T / LSTM_CT)

__device__ __forceinline__ float fast_exp(float x) {
    return __builtin_amdgcn_exp2f(x * 1.44269504088896f);
}
__device__ __forceinline__ float fsigm(float x) {
    // 1/(1+e^-x); rcp is 1-ulp approx, plenty under the 1.1e-2 threshold
    return __builtin_amdgcn_rcpf(1.0f + fast_exp(-x));
}
__device__ __forceinline__ float ftanh(float x) {
    x = fminf(15.0f, fmaxf(-15.0f, x));   // avoid inf/inf
    float e = fast_exp(2.0f * x);
    return (e - 1.0f) * __builtin_amdgcn_rcpf(e + 1.0f);
}
__device__ __forceinline__ float dot4(float4 w, float4 q, float acc) {
    acc = fmaf(w.x, q.x, acc);
    acc = fmaf(w.y, q.y, acc);
    acc = fmaf(w.z, q.z, acc);
    acc = fmaf(w.w, q.w, acc);
    return acc;
}

// One wave per batch row. Lane g owns gate row g of LSTM1 (4*H1 = 64 gates);
// lanes 0..15 also own the 16 gate rows of LSTM2; lanes 0..15 own c1/h1 state,
// lanes 0..3 own c2/h2 state. h-state broadcast via tiny LDS buffers.
__global__ __launch_bounds__(64, 2)
void lstm_fused_kernel(const float* __restrict__ x,
        const float* __restrict__ Wih1, const float* __restrict__ Whh1,
        const float* __restrict__ bih1, const float* __restrict__ bhh1,
        const float* __restrict__ Wih2, const float* __restrict__ Whh2,
        const float* __restrict__ bih2, const float* __restrict__ bhh2,
        const float* __restrict__ Wfc,  const float* __restrict__ bfc,
        float* __restrict__ out)
{
    __shared__ __align__(16) float xbuf[2][LSTM_CT * 64];  // double-buffered x chunk
    __shared__ __align__(16) float h1buf[16];
    __shared__ __align__(16) float rbuf[16];               // relu(h1)
    __shared__ __align__(16) float h2buf[4];

    const int lane = threadIdx.x;
    const size_t b = blockIdx.x;

    // ---- weight preload (per-lane rows in registers) ----
    float4 wih[16];
#pragma unroll
    for (int k = 0; k < 16; ++k)
        wih[k] = *(const float4*)(Wih1 + lane * 64 + k * 4);
    float4 whh[4];
#pragma unroll
    for (int k = 0; k < 4; ++k)
        whh[k] = *(const float4*)(Whh1 + lane * 16 + k * 4);
    const float bias1 = bih1[lane] + bhh1[lane];

    float4 wih2[4] = {};
    float4 whh2 = {};
    float bias2 = 0.0f;
    if (lane < 16) {
#pragma unroll
        for (int k = 0; k < 4; ++k)
            wih2[k] = *(const float4*)(Wih2 + lane * 16 + k * 4);
        whh2 = *(const float4*)(Whh2 + lane * 4);
        bias2 = bih2[lane] + bhh2[lane];
    }
    const float4 wfc  = *(const float4*)(Wfc + lane * 4);
    const float bfcv  = bfc[lane];

    float c1 = 0.f, h1 = 0.f, c2 = 0.f, h2 = 0.f;
    if (lane < 16) { h1buf[lane] = 0.f; rbuf[lane] = 0.f; }
    if (lane < 4)  h2buf[lane] = 0.f;

    const float* xb = x + b * (size_t)(LSTM_T * 64);

    // ---- stage chunk 0 ----
    float4 stage[4];
#pragma unroll
    for (int i = 0; i < 4; ++i)
        stage[i] = *(const float4*)(xb + i * 256 + lane * 4);
#pragma unroll
    for (int i = 0; i < 4; ++i)
        *(float4*)(&xbuf[0][i * 256 + lane * 4]) = stage[i];

    for (int c = 0; c < LSTM_NC; ++c) {
        const int cur = c & 1;
        const bool more = (c + 1 < LSTM_NC);
        // prefetch next chunk into registers; HBM latency hides under the
        // 16-timestep compute below (compiler-managed vmcnt)
        if (more) {
            const float* src = xb + (size_t)(c + 1) * (LSTM_CT * 64);
#pragma unroll
            for (int i = 0; i < 4; ++i)
                stage[i] = *(const float4*)(src + i * 256 + lane * 4);
        }

        for (int tt = 0; tt < LSTM_CT; ++tt) {
            const float* xt = &xbuf[cur][tt * 64];
            // gate preactivation: W_ih1[g,:] . x_t  (uniform LDS broadcast)
            float ac0 = bias1, ac1 = 0.f, ac2 = 0.f, ac3 = 0.f;
#pragma unroll
            for (int k = 0; k < 4; ++k) {
                ac0 = dot4(wih[4 * k + 0], *(const float4*)(xt + (4 * k + 0) * 4), ac0);
                ac1 = dot4(wih[4 * k + 1], *(const float4*)(xt + (4 * k + 1) * 4), ac1);
                ac2 = dot4(wih[4 * k + 2], *(const float4*)(xt + (4 * k + 2) * 4), ac2);
                ac3 = dot4(wih[4 * k + 3], *(const float4*)(xt + (4 * k + 3) * 4), ac3);
            }
            // recurrent: W_hh1[g,:] . h1
            ac0 = dot4(whh[0], *(const float4*)(&h1buf[0]),  ac0);
            ac1 = dot4(whh[1], *(const float4*)(&h1buf[4]),  ac1);
            ac2 = dot4(whh[2], *(const float4*)(&h1buf[8]),  ac2);
            ac3 = dot4(whh[3], *(const float4*)(&h1buf[12]), ac3);
            float pre = (ac0 + ac1) + (ac2 + ac3);

            // gate order i(0-15) f(16-31) g(32-47,tanh) o(48-63)
            bool isg = (lane >= 32) && (lane < 48);
            float act = isg ? ftanh(pre) : fsigm(pre);
            float fg = __shfl(act, lane + 16);
            float gg = __shfl(act, lane + 32);
            float og = __shfl(act, lane + 48);
            c1 = fmaf(fg, c1, act * gg);          // valid on lanes 0..15
            h1 = og * ftanh(c1);
            float r = fmaxf(h1, 0.f);
            if (lane < 16) { h1buf[lane] = h1; rbuf[lane] = r; }

            // ---- LSTM2 (gates on lanes 0..15): input = relu(h1) ----
            float p2 = bias2;
            p2 = dot4(wih2[0], *(const float4*)(&rbuf[0]),  p2);
            p2 = dot4(wih2[1], *(const float4*)(&rbuf[4]),  p2);
            p2 = dot4(wih2[2], *(const float4*)(&rbuf[8]),  p2);
            p2 = dot4(wih2[3], *(const float4*)(&rbuf[12]), p2);
            p2 = dot4(whh2, *(const float4*)(&h2buf[0]), p2);
            // gate order i(0-3) f(4-7) g(8-11,tanh) o(12-15)
            bool isg2 = (lane >= 8) && (lane < 12);
            float act2 = isg2 ? ftanh(p2) : fsigm(p2);
            float f2 = __shfl(act2, lane + 4);
            float g2 = __shfl(act2, lane + 8);
            float o2 = __shfl(act2, lane + 12);
            c2 = fmaf(f2, c2, act2 * g2);         // valid on lanes 0..3
            h2 = o2 * ftanh(c2);
            if (lane < 4) h2buf[lane] = h2;
        }

        // write prefetched chunk into the other LDS buffer (after all reads of cur)
        if (more) {
            const int nxt = cur ^ 1;
#pragma unroll
            for (int i = 0; i < 4; ++i)
                *(float4*)(&xbuf[nxt][i * 256 + lane * 4]) = stage[i];
        }
    }

    // ---- FC + sigmoid: out[b,d] = sigm(W_fc[d,:].h2 + b_fc[d]), lane = d ----
    float4 h2q = *(const float4*)(&h2buf[0]);
    float acc = dot4(wfc, h2q, bfcv);
    out[b * 64 + lane] = fsigm(acc);
}

extern "C" void kernel_launch(void* const* d_in, const int* in_sizes, int n_in,
                              void* d_out, int out_size, void* d_ws, size_t ws_size,
                              hipStream_t stream) {
    const float* x    = (const float*)d_in[0];
    const float* Wih1 = (const float*)d_in[1];
    const float* Whh1 = (const float*)d_in[2];
    const float* bih1 = (const float*)d_in[3];
    const float* bhh1 = (const float*)d_in[4];
    const float* Wih2 = (const float*)d_in[5];
    const float* Whh2 = (const float*)d_in[6];
    const float* bih2 = (const float*)d_in[7];
    const float* bhh2 = (const float*)d_in[8];
    const float* Wfc  = (const float*)d_in[9];
    const float* bfc  = (const float*)d_in[10];
    float* out = (float*)d_out;

    lstm_fused_kernel<<<dim3(2048), dim3(64), 0, stream>>>(
        x, Wih1, Whh1, bih1, bhh1, Wih2, Whh2, bih2, bhh2, Wfc, bfc, out);
}

// Round 2
// 255.390 us; speedup vs baseline: 2.0515x; 2.0515x over previous
//
#include <hip/hip_runtime.h>
#include <hip/hip_bf16.h>

#define T_ALL 512
#define TB 16
#define NB (T_ALL / TB)

typedef __attribute__((ext_vector_type(8))) short bf16x8;
typedef __attribute__((ext_vector_type(4))) float f32x4;

__device__ __forceinline__ float fsigm(float x) {
    // 1/(1+2^(-x*log2e))
    return __builtin_amdgcn_rcpf(1.0f + __builtin_amdgcn_exp2f(-1.44269504f * x));
}
__device__ __forceinline__ float ftanh(float x) {
    // tanh(x) = 2*sigm(2x)-1; saturates gracefully (exp2->inf -> rcp->0)
    float s = fsigm(2.0f * x);
    return fmaf(2.0f, s, -1.0f);
}
__device__ __forceinline__ unsigned pack2bf16(float a, float b) {
    unsigned ua = __float_as_uint(a), ub = __float_as_uint(b);
    ua += 0x7FFFu + ((ua >> 16) & 1u);   // RNE
    ub += 0x7FFFu + ((ub >> 16) & 1u);
    return (ua >> 16) | (ub & 0xFFFF0000u);
}
__device__ __forceinline__ bf16x8 make_frag(float4 lo, float4 hi) {
    union { unsigned u[4]; bf16x8 v; } r;
    r.u[0] = pack2bf16(lo.x, lo.y);
    r.u[1] = pack2bf16(lo.z, lo.w);
    r.u[2] = pack2bf16(hi.x, hi.y);
    r.u[3] = pack2bf16(hi.z, hi.w);
    return r.v;
}
__device__ __forceinline__ float dot4(float4 w, float4 q, float acc) {
    acc = fmaf(w.x, q.x, acc);
    acc = fmaf(w.y, q.y, acc);
    acc = fmaf(w.z, q.z, acc);
    acc = fmaf(w.w, q.w, acc);
    return acc;
}

// One wave per batch row. xg (input gates for 16 timesteps) computed by MFMA
// into LDS; the sequential scan then does only the recurrent work.
// Gate lanes: LSTM1 g = lane (i:0-15 f:16-31 g:32-47 o:48-63);
// LSTM2 gates on lanes 0-15 (i:0-3 f:4-7 g:8-11 o:12-15).
__global__ __launch_bounds__(64, 2)
void lstm_fused_mfma(const float* __restrict__ x,
        const float* __restrict__ Wih1, const float* __restrict__ Whh1,
        const float* __restrict__ bih1, const float* __restrict__ bhh1,
        const float* __restrict__ Wih2, const float* __restrict__ Whh2,
        const float* __restrict__ bih2, const float* __restrict__ bhh2,
        const float* __restrict__ Wfc,  const float* __restrict__ bfc,
        float* __restrict__ out)
{
    __shared__ __align__(16) float xg[TB * 64];   // gate preacts for one 16-step block
    __shared__ __align__(16) float h1buf[16];
    __shared__ __align__(16) float rbuf[16];
    __shared__ __align__(16) float h2buf[4];

    const int lane = threadIdx.x;
    const int tl = lane & 15;     // A-frag row (timestep) / B,C col
    const int kh = lane >> 4;     // k-group
    const size_t b = blockIdx.x;

    // ---- B fragments: Wih1^T, 4 N-tiles x 2 K-steps, bf16 (32 VGPRs) ----
    bf16x8 wb[4][2];
#pragma unroll
    for (int n = 0; n < 4; ++n)
#pragma unroll
        for (int kk = 0; kk < 2; ++kk) {
            const float* wp = Wih1 + (size_t)(n * 16 + tl) * 64 + kk * 32 + kh * 8;
            wb[n][kk] = make_frag(*(const float4*)wp, *(const float4*)(wp + 4));
        }
    float bias1[4];
#pragma unroll
    for (int n = 0; n < 4; ++n)
        bias1[n] = bih1[n * 16 + tl] + bhh1[n * 16 + tl];

    // ---- small weights in registers (index-clamped: uniform control flow) ----
    float4 whh[4];
#pragma unroll
    for (int k = 0; k < 4; ++k)
        whh[k] = *(const float4*)(Whh1 + lane * 16 + k * 4);
    float4 wih2[4];
#pragma unroll
    for (int k = 0; k < 4; ++k)
        wih2[k] = *(const float4*)(Wih2 + (lane & 15) * 16 + k * 4);
    const float4 whh2 = *(const float4*)(Whh2 + (lane & 15) * 4);
    const float bias2 = bih2[lane & 15] + bhh2[lane & 15];
    const float4 wfc = *(const float4*)(Wfc + lane * 4);
    const float bfcv = bfc[lane];

    float c1 = 0.f, h1 = 0.f, c2 = 0.f, h2 = 0.f;
    if (lane < 16) { h1buf[lane] = 0.f; rbuf[lane] = 0.f; }
    if (lane < 4)  h2buf[lane] = 0.f;

    const float* xb = x + b * (size_t)(T_ALL * 64);

    // ---- prefetch x block 0: lane -> x[t=tl][d = kk*32 + kh*8 + 0..7] ----
    float4 xpf[4];
#pragma unroll
    for (int kk = 0; kk < 2; ++kk)
#pragma unroll
        for (int hf = 0; hf < 2; ++hf)
            xpf[kk * 2 + hf] = *(const float4*)(xb + tl * 64 + kk * 32 + kh * 8 + hf * 4);

    for (int c = 0; c < NB; ++c) {
        // convert staged x to A-frags, then kick next block's loads
        bf16x8 a0 = make_frag(xpf[0], xpf[1]);
        bf16x8 a1 = make_frag(xpf[2], xpf[3]);
        if (c + 1 < NB) {
            const float* src = xb + (size_t)(c + 1) * (TB * 64);
#pragma unroll
            for (int kk = 0; kk < 2; ++kk)
#pragma unroll
                for (int hf = 0; hf < 2; ++hf)
                    xpf[kk * 2 + hf] = *(const float4*)(src + tl * 64 + kk * 32 + kh * 8 + hf * 4);
        }

        // xg[t][g] = bias + x_t . Wih1[g,:]  via 8 MFMAs
#pragma unroll
        for (int n = 0; n < 4; ++n) {
            f32x4 acc = {bias1[n], bias1[n], bias1[n], bias1[n]};
            acc = __builtin_amdgcn_mfma_f32_16x16x32_bf16(a0, wb[n][0], acc, 0, 0, 0);
            acc = __builtin_amdgcn_mfma_f32_16x16x32_bf16(a1, wb[n][1], acc, 0, 0, 0);
            // C layout: col = lane&15, row = (lane>>4)*4 + r
#pragma unroll
            for (int r = 0; r < 4; ++r)
                xg[(kh * 4 + r) * 64 + n * 16 + tl] = acc[r];
        }

        // ---- sequential scan over the 16 timesteps of this block ----
#pragma unroll 4
        for (int tt = 0; tt < TB; ++tt) {
            float pre = xg[tt * 64 + lane];
            float ac0 = dot4(whh[0], *(const float4*)(&h1buf[0]),  0.f);
            float ac1 = dot4(whh[1], *(const float4*)(&h1buf[4]),  0.f);
            float ac2 = dot4(whh[2], *(const float4*)(&h1buf[8]),  0.f);
            float ac3 = dot4(whh[3], *(const float4*)(&h1buf[12]), 0.f);
            pre += (ac0 + ac1) + (ac2 + ac3);

            bool isg = (lane >= 32) && (lane < 48);
            float s = fsigm(isg ? 2.0f * pre : pre);
            float act = isg ? fmaf(2.0f, s, -1.0f) : s;
            float fg = __shfl(act, lane + 16);
            float gg = __shfl(act, lane + 32);
            float og = __shfl(act, lane + 48);
            c1 = fmaf(fg, c1, act * gg);          // valid on lanes 0..15
            h1 = og * ftanh(c1);
            float rv = fmaxf(h1, 0.f);
            if (lane < 16) { h1buf[lane] = h1; rbuf[lane] = rv; }

            // LSTM2
            float p2 = bias2;
            p2 = dot4(wih2[0], *(const float4*)(&rbuf[0]),  p2);
            p2 = dot4(wih2[1], *(const float4*)(&rbuf[4]),  p2);
            p2 = dot4(wih2[2], *(const float4*)(&rbuf[8]),  p2);
            p2 = dot4(wih2[3], *(const float4*)(&rbuf[12]), p2);
            p2 = dot4(whh2, *(const float4*)(&h2buf[0]), p2);
            bool isg2 = (lane >= 8) && (lane < 12);
            float s2 = fsigm(isg2 ? 2.0f * p2 : p2);
            float act2 = isg2 ? fmaf(2.0f, s2, -1.0f) : s2;
            float f2 = __shfl(act2, lane + 4);
            float g2 = __shfl(act2, lane + 8);
            float o2 = __shfl(act2, lane + 12);
            c2 = fmaf(f2, c2, act2 * g2);         // valid on lanes 0..3
            h2 = o2 * ftanh(c2);
            if (lane < 4) h2buf[lane] = h2;
        }
    }

    // ---- FC + sigmoid ----
    float4 h2q = *(const float4*)(&h2buf[0]);
    out[b * 64 + lane] = fsigm(dot4(wfc, h2q, bfcv));
}

extern "C" void kernel_launch(void* const* d_in, const int* in_sizes, int n_in,
                              void* d_out, int out_size, void* d_ws, size_t ws_size,
                              hipStream_t stream) {
    const float* x    = (const float*)d_in[0];
    const float* Wih1 = (const float*)d_in[1];
    const float* Whh1 = (const float*)d_in[2];
    const float* bih1 = (const float*)d_in[3];
    const float* bhh1 = (const float*)d_in[4];
    const float* Wih2 = (const float*)d_in[5];
    const float* Whh2 = (const float*)d_in[6];
    const float* bih2 = (const float*)d_in[7];
    const float* bhh2 = (const float*)d_in[8];
    const float* Wfc  = (const float*)d_in[9];
    const float* bfc  = (const float*)d_in[10];
    float* out = (float*)d_out;

    lstm_fused_mfma<<<dim3(2048), dim3(64), 0, stream>>>(
        x, Wih1, Whh1, bih1, bhh1, Wih2, Whh2, bih2, bhh2, Wfc, bfc, out);
}

// Round 3
// 207.556 us; speedup vs baseline: 2.5243x; 1.2305x over previous
//
#include <hip/hip_runtime.h>
#include <hip/hip_bf16.h>

#define T_ALL 512
#define TB 16
#define NB (T_ALL / TB)
#define LOG2E 1.44269504088896f

typedef __attribute__((ext_vector_type(8))) short bf16x8;
typedef __attribute__((ext_vector_type(4))) float f32x4;

__device__ __forceinline__ unsigned pack2bf16(float a, float b) {
    unsigned ua = __float_as_uint(a), ub = __float_as_uint(b);
    ua += 0x7FFFu + ((ua >> 16) & 1u);   // RNE
    ub += 0x7FFFu + ((ub >> 16) & 1u);
    return (ua >> 16) | (ub & 0xFFFF0000u);
}
__device__ __forceinline__ bf16x8 make_frag(float4 lo, float4 hi) {
    union { unsigned u[4]; bf16x8 v; } r;
    r.u[0] = pack2bf16(lo.x, lo.y);
    r.u[1] = pack2bf16(lo.z, lo.w);
    r.u[2] = pack2bf16(hi.x, hi.y);
    r.u[3] = pack2bf16(hi.z, hi.w);
    return r.v;
}
__device__ __forceinline__ float4 scale4(float4 v, float s) {
    return make_float4(v.x * s, v.y * s, v.z * s, v.w * s);
}
// float2 FMA - compiler should emit v_pk_fma_f32
__device__ __forceinline__ float2 pkfma(float2 a, float2 b, float2 c) {
    return make_float2(fmaf(a.x, b.x, c.x), fmaf(a.y, b.y, c.y));
}
__device__ __forceinline__ float fsigm(float x) {
    return __builtin_amdgcn_rcpf(1.0f + __builtin_amdgcn_exp2f(-LOG2E * x));
}

// One wave per batch row. xg (pre-scaled gate preacts, 16 steps) via MFMA into
// LDS. Scan: lane = LSTM1 gate (i:0-15 f:16-31 g:32-47 o:48-63). LSTM2
// distributed: gate g2 = lane&15, k-slice s2 = lane>>4 (5 MACs/lane), reduced
// with 2 shfl_xor. All activation scales folded into weights at setup.
__global__ __launch_bounds__(64, 2)
void lstm_fused_v3(const float* __restrict__ x,
        const float* __restrict__ Wih1, const float* __restrict__ Whh1,
        const float* __restrict__ bih1, const float* __restrict__ bhh1,
        const float* __restrict__ Wih2, const float* __restrict__ Whh2,
        const float* __restrict__ bih2, const float* __restrict__ bhh2,
        const float* __restrict__ Wfc,  const float* __restrict__ bfc,
        float* __restrict__ out)
{
    __shared__ __align__(16) float xg[TB * 64];
    __shared__ __align__(16) float h1buf[16];

    const int lane = threadIdx.x;
    const int tl = lane & 15;
    const int kh = lane >> 4;
    const size_t b = blockIdx.x;

    // ---- per-lane activation constants ----
    const float sc1 = (kh == 2) ? 2.0f * LOG2E : LOG2E;   // LSTM1: lane's gate block
    const float aA1 = (kh == 2) ? 2.0f : 1.0f;
    const float aB1 = (kh == 2) ? -1.0f : 0.0f;
    const int g2 = lane & 15;             // LSTM2 gate (i:0-3 f:4-7 g:8-11 o:12-15)
    const int s2 = lane >> 4;             // LSTM2 k-slice
    const bool tan2 = ((g2 >> 2) == 2);
    const float sc2 = tan2 ? 2.0f * LOG2E : LOG2E;
    const float aA2 = tan2 ? 2.0f : 1.0f;
    const float aB2 = tan2 ? -1.0f : 0.0f;

    // ---- B fragments for xg MFMA: Wih1^T, pre-scaled per gate block ----
    bf16x8 wb[4][2];
    float bias1[4];
#pragma unroll
    for (int n = 0; n < 4; ++n) {
        const float scn = (n == 2) ? 2.0f * LOG2E : LOG2E;
#pragma unroll
        for (int kk = 0; kk < 2; ++kk) {
            const float* wp = Wih1 + (size_t)(n * 16 + tl) * 64 + kk * 32 + kh * 8;
            wb[n][kk] = make_frag(scale4(*(const float4*)wp, scn),
                                  scale4(*(const float4*)(wp + 4), scn));
        }
        bias1[n] = (bih1[n * 16 + tl] + bhh1[n * 16 + tl]) * scn;
    }

    // ---- recurrent weights, pre-scaled, as float2 ----
    float2 whh[8];
    {
        const float* wp = Whh1 + lane * 16;
#pragma unroll
        for (int k = 0; k < 8; ++k)
            whh[k] = make_float2(wp[2 * k] * sc1, wp[2 * k + 1] * sc1);
    }
    // ---- LSTM2 weights: lane covers r[4*s2..4*s2+3] and h2[s2] for gate g2 ----
    const float* w2p = Wih2 + g2 * 16 + s2 * 4;
    const float2 w2a = make_float2(w2p[0] * sc2, w2p[1] * sc2);
    const float2 w2b = make_float2(w2p[2] * sc2, w2p[3] * sc2);
    const float w2h = Whh2[g2 * 4 + s2] * sc2;
    const float bias2l = (s2 == 0) ? (bih2[g2] + bhh2[g2]) * sc2 : 0.0f;

    const float4 wfc = *(const float4*)(Wfc + lane * 4);
    const float bfcv = bfc[lane];

    float c1 = 0.f, h1 = 0.f, c2 = 0.f, h2 = 0.f, h2s = 0.f;
    if (lane < 16) h1buf[lane] = 0.f;

    const float* xb = x + b * (size_t)(T_ALL * 64);

    // ---- prefetch x block 0 ----
    float4 xpf[4];
#pragma unroll
    for (int kk = 0; kk < 2; ++kk)
#pragma unroll
        for (int hf = 0; hf < 2; ++hf)
            xpf[kk * 2 + hf] = *(const float4*)(xb + tl * 64 + kk * 32 + kh * 8 + hf * 4);

    for (int c = 0; c < NB; ++c) {
        bf16x8 a0 = make_frag(xpf[0], xpf[1]);
        bf16x8 a1 = make_frag(xpf[2], xpf[3]);
        if (c + 1 < NB) {
            const float* src = xb + (size_t)(c + 1) * (TB * 64);
#pragma unroll
            for (int kk = 0; kk < 2; ++kk)
#pragma unroll
                for (int hf = 0; hf < 2; ++hf)
                    xpf[kk * 2 + hf] = *(const float4*)(src + tl * 64 + kk * 32 + kh * 8 + hf * 4);
        }

        // xg[t][g] = scaled(bias + x_t . Wih1[g,:]) via 8 MFMAs
#pragma unroll
        for (int n = 0; n < 4; ++n) {
            f32x4 acc = {bias1[n], bias1[n], bias1[n], bias1[n]};
            acc = __builtin_amdgcn_mfma_f32_16x16x32_bf16(a0, wb[n][0], acc, 0, 0, 0);
            acc = __builtin_amdgcn_mfma_f32_16x16x32_bf16(a1, wb[n][1], acc, 0, 0, 0);
#pragma unroll
            for (int r = 0; r < 4; ++r)
                xg[(kh * 4 + r) * 64 + n * 16 + tl] = acc[r];
        }

        // ---- sequential scan ----
#pragma unroll
        for (int tt = 0; tt < TB; ++tt) {
            const float4 q0 = *(const float4*)(&h1buf[0]);
            const float4 q1 = *(const float4*)(&h1buf[4]);
            const float4 q2 = *(const float4*)(&h1buf[8]);
            const float4 q3 = *(const float4*)(&h1buf[12]);

            float2 acc01 = make_float2(xg[tt * 64 + lane], 0.f);
            float2 acc23 = make_float2(0.f, 0.f);
            acc01 = pkfma(whh[0], make_float2(q0.x, q0.y), acc01);
            acc23 = pkfma(whh[1], make_float2(q0.z, q0.w), acc23);
            acc01 = pkfma(whh[2], make_float2(q1.x, q1.y), acc01);
            acc23 = pkfma(whh[3], make_float2(q1.z, q1.w), acc23);
            acc01 = pkfma(whh[4], make_float2(q2.x, q2.y), acc01);
            acc23 = pkfma(whh[5], make_float2(q2.z, q2.w), acc23);
            acc01 = pkfma(whh[6], make_float2(q3.x, q3.y), acc01);
            acc23 = pkfma(whh[7], make_float2(q3.z, q3.w), acc23);
            const float pre = (acc01.x + acc23.x) + (acc01.y + acc23.y);

            const float e1 = __builtin_amdgcn_exp2f(-pre);       // weights pre-scaled
            const float s1 = __builtin_amdgcn_rcpf(1.0f + e1);
            const float act = fmaf(aA1, s1, aB1);                // sigm or tanh
            const float fg = __shfl(act, lane + 16);
            const float gg = __shfl(act, lane + 32);
            const float og = __shfl(act, lane + 48);
            c1 = fmaf(fg, c1, act * gg);                         // valid lanes 0-15
            const float ec = __builtin_amdgcn_exp2f(-2.0f * LOG2E * c1);
            h1 = og * fmaf(2.0f, __builtin_amdgcn_rcpf(1.0f + ec), -1.0f);
            if (lane < 16) h1buf[lane] = h1;

            // ---- LSTM2, distributed over all 64 lanes ----
            const float4 rq = *(const float4*)(&h1buf[s2 * 4]);  // new h1 slice
            const float2 r01 = make_float2(fmaxf(rq.x, 0.f), fmaxf(rq.y, 0.f));
            const float2 r23 = make_float2(fmaxf(rq.z, 0.f), fmaxf(rq.w, 0.f));
            float2 a2 = make_float2(bias2l, w2h * h2s);
            a2 = pkfma(w2a, r01, a2);
            a2 = pkfma(w2b, r23, a2);
            float p2 = a2.x + a2.y;
            p2 += __shfl_xor(p2, 16);
            p2 += __shfl_xor(p2, 32);
            const float e2 = __builtin_amdgcn_exp2f(-p2);
            const float s2v = __builtin_amdgcn_rcpf(1.0f + e2);
            const float act2 = fmaf(aA2, s2v, aB2);
            const float f2 = __shfl(act2, lane + 4);
            const float gv = __shfl(act2, lane + 8);
            const float ov = __shfl(act2, lane + 12);
            c2 = fmaf(f2, c2, act2 * gv);                        // valid g2<4
            const float ec2 = __builtin_amdgcn_exp2f(-2.0f * LOG2E * c2);
            h2 = ov * fmaf(2.0f, __builtin_amdgcn_rcpf(1.0f + ec2), -1.0f);
            h2s = __shfl(h2, s2);                                // h2[s2] for next step
        }
    }

    // ---- FC + sigmoid: out[b,d] = sigm(Wfc[d,:].h2 + bfc[d]) ----
    const float4 h2q = make_float4(__shfl(h2, 0), __shfl(h2, 1),
                                   __shfl(h2, 2), __shfl(h2, 3));
    float accf = bfcv;
    accf = fmaf(wfc.x, h2q.x, accf);
    accf = fmaf(wfc.y, h2q.y, accf);
    accf = fmaf(wfc.z, h2q.z, accf);
    accf = fmaf(wfc.w, h2q.w, accf);
    out[b * 64 + lane] = fsigm(accf);
}

extern "C" void kernel_launch(void* const* d_in, const int* in_sizes, int n_in,
                              void* d_out, int out_size, void* d_ws, size_t ws_size,
                              hipStream_t stream) {
    const float* x    = (const float*)d_in[0];
    const float* Wih1 = (const float*)d_in[1];
    const float* Whh1 = (const float*)d_in[2];
    const float* bih1 = (const float*)d_in[3];
    const float* bhh1 = (const float*)d_in[4];
    const float* Wih2 = (const float*)d_in[5];
    const float* Whh2 = (const float*)d_in[6];
    const float* bih2 = (const float*)d_in[7];
    const float* bhh2 = (const float*)d_in[8];
    const float* Wfc  = (const float*)d_in[9];
    const float* bfc  = (const float*)d_in[10];
    float* out = (float*)d_out;

    lstm_fused_v3<<<dim3(2048), dim3(64), 0, stream>>>(
        x, Wih1, Whh1, bih1, bhh1, Wih2, Whh2, bih2, bhh2, Wfc, bfc, out);
}

// Round 4
// 186.083 us; speedup vs baseline: 2.8155x; 1.1154x over previous
//
#include <hip/hip_runtime.h>
#include <hip/hip_bf16.h>

#define T_ALL 512
#define TB 16
#define NB (T_ALL / TB)
#define LOG2E 1.44269504088896f
#define XSTR 20   // padded row stride (floats) of transposed xg: conflict-free b128

typedef __attribute__((ext_vector_type(8))) short bf16x8;
typedef __attribute__((ext_vector_type(4))) float f32x4;

// DPP / swizzle helpers (compile-time patterns, VALU / no-addr DS)
#define DPPF(v, CTRL) __uint_as_float((unsigned)__builtin_amdgcn_update_dpp(0, (int)__float_as_uint(v), (CTRL), 0xF, 0xF, true))
#define SWZF(v, PAT)  __uint_as_float((unsigned)__builtin_amdgcn_ds_swizzle((int)__float_as_uint(v), (PAT)))

__device__ __forceinline__ unsigned pack2bf16(float a, float b) {
    unsigned ua = __float_as_uint(a), ub = __float_as_uint(b);
    ua += 0x7FFFu + ((ua >> 16) & 1u);   // RNE
    ub += 0x7FFFu + ((ub >> 16) & 1u);
    return (ua >> 16) | (ub & 0xFFFF0000u);
}
__device__ __forceinline__ bf16x8 make_frag(float4 lo, float4 hi) {
    union { unsigned u[4]; bf16x8 v; } r;
    r.u[0] = pack2bf16(lo.x, lo.y);
    r.u[1] = pack2bf16(lo.z, lo.w);
    r.u[2] = pack2bf16(hi.x, hi.y);
    r.u[3] = pack2bf16(hi.z, hi.w);
    return r.v;
}
__device__ __forceinline__ float4 scale4(float4 v, float s) {
    return make_float4(v.x * s, v.y * s, v.z * s, v.w * s);
}
__device__ __forceinline__ float2 pkfma(float2 a, float2 b, float2 c) {
    return make_float2(fmaf(a.x, b.x, c.x), fmaf(a.y, b.y, c.y));
}
__device__ __forceinline__ float fsigm(float x) {
    return __builtin_amdgcn_rcpf(1.0f + __builtin_amdgcn_exp2f(-LOG2E * x));
}

// One wave per batch row.
// LSTM1 scan layout: lane = 4*j + T  (j = h-index 0..15, T = gate type i/f/g/o)
//   -> gate combine is intra-quad (DPP quad_perm broadcasts), state replicated x4.
// LSTM2 layout: lane = 16*m + 4*T + s (m = h-index, T = type, s = k-slice)
//   -> slice reduce intra-quad (DPP), type combine via ds_swizzle xor4/8/12.
// LSTM2 runs LAGGED by one step (uses h1(t-1)) so its chain overlaps LSTM1's.
__global__ __launch_bounds__(64, 2)
void lstm_fused_v4(const float* __restrict__ x,
        const float* __restrict__ Wih1, const float* __restrict__ Whh1,
        const float* __restrict__ bih1, const float* __restrict__ bhh1,
        const float* __restrict__ Wih2, const float* __restrict__ Whh2,
        const float* __restrict__ bih2, const float* __restrict__ bhh2,
        const float* __restrict__ Wfc,  const float* __restrict__ bfc,
        float* __restrict__ out)
{
    __shared__ __align__(16) float xs[64 * XSTR];   // xg transposed: [gate-lane][t]
    __shared__ __align__(16) float h1buf[16];

    const int lane = threadIdx.x;
    const int tl = lane & 15;     // MFMA: A row (timestep) / C col
    const int kh = lane >> 4;     // MFMA: k-group
    const size_t b = blockIdx.x;

    // ---- LSTM1 scan-lane roles ----
    const int T1 = lane & 3;
    const int j1 = lane >> 2;
    const int g1 = T1 * 16 + j1;                       // row in Wih1/Whh1/bias
    const float sc1 = (T1 == 2) ? 2.0f * LOG2E : LOG2E;
    const float aA1 = (T1 == 2) ? 2.0f : 1.0f;
    const float aB1 = (T1 == 2) ? -1.0f : 0.0f;

    // ---- LSTM2 lane roles ----
    const int m2 = lane >> 4;
    const int T2 = (lane >> 2) & 3;
    const int s2v = lane & 3;
    const int row2 = T2 * 4 + m2;                      // row in Wih2/Whh2/bias
    const float sc2 = (T2 == 2) ? 2.0f * LOG2E : LOG2E;
    const float aA2 = (T2 == 2) ? 2.0f : 1.0f;
    const float aB2 = (T2 == 2) ? -1.0f : 0.0f;

    // ---- B fragments for xg MFMA: Wih1^T, pre-scaled per gate block ----
    bf16x8 wb[4][2];
    float bias1[4];
#pragma unroll
    for (int n = 0; n < 4; ++n) {
        const float scn = (n == 2) ? 2.0f * LOG2E : LOG2E;
#pragma unroll
        for (int kk = 0; kk < 2; ++kk) {
            const float* wp = Wih1 + (size_t)(n * 16 + tl) * 64 + kk * 32 + kh * 8;
            wb[n][kk] = make_frag(scale4(*(const float4*)wp, scn),
                                  scale4(*(const float4*)(wp + 4), scn));
        }
        bias1[n] = (bih1[n * 16 + tl] + bhh1[n * 16 + tl]) * scn;
    }

    // ---- recurrent weights (remapped rows), pre-scaled, as float2 ----
    float2 whh[8];
    {
        const float* wp = Whh1 + g1 * 16;
#pragma unroll
        for (int k = 0; k < 8; ++k)
            whh[k] = make_float2(wp[2 * k] * sc1, wp[2 * k + 1] * sc1);
    }
    const float* w2p = Wih2 + row2 * 16 + s2v * 4;
    const float2 w2a = make_float2(w2p[0] * sc2, w2p[1] * sc2);
    const float2 w2b = make_float2(w2p[2] * sc2, w2p[3] * sc2);
    const float w2h = Whh2[row2 * 4 + s2v] * sc2;
    const float bias2l = (s2v == 0) ? (bih2[row2] + bhh2[row2]) * sc2 : 0.0f;

    const float4 wfc = *(const float4*)(Wfc + lane * 4);
    const float bfcv = bfc[lane];

    float c1 = 0.f, h1 = 0.f, c2 = 0.f, h2 = 0.f, h2s = 0.f;
    if (lane < 16) h1buf[lane] = 0.f;

    const float* xb = x + b * (size_t)(T_ALL * 64);

    // ---- prefetch x block 0 ----
    float4 xpf[4];
#pragma unroll
    for (int kk = 0; kk < 2; ++kk)
#pragma unroll
        for (int hf = 0; hf < 2; ++hf)
            xpf[kk * 2 + hf] = *(const float4*)(xb + tl * 64 + kk * 32 + kh * 8 + hf * 4);

    for (int c = 0; c < NB; ++c) {
        bf16x8 a0 = make_frag(xpf[0], xpf[1]);
        bf16x8 a1 = make_frag(xpf[2], xpf[3]);
        if (c + 1 < NB) {
            const float* src = xb + (size_t)(c + 1) * (TB * 64);
#pragma unroll
            for (int kk = 0; kk < 2; ++kk)
#pragma unroll
                for (int hf = 0; hf < 2; ++hf)
                    xpf[kk * 2 + hf] = *(const float4*)(src + tl * 64 + kk * 32 + kh * 8 + hf * 4);
        }

        // xg via 8 MFMAs, stored TRANSPOSED: row = 4*tl + n (= scan lane), col = t
#pragma unroll
        for (int n = 0; n < 4; ++n) {
            f32x4 acc = {bias1[n], bias1[n], bias1[n], bias1[n]};
            acc = __builtin_amdgcn_mfma_f32_16x16x32_bf16(a0, wb[n][0], acc, 0, 0, 0);
            acc = __builtin_amdgcn_mfma_f32_16x16x32_bf16(a1, wb[n][1], acc, 0, 0, 0);
            *(float4*)(&xs[(4 * tl + n) * XSTR + kh * 4]) =
                make_float4(acc[0], acc[1], acc[2], acc[3]);
        }

        // ---- sequential scan over 16 timesteps ----
#pragma unroll
        for (int t4 = 0; t4 < 4; ++t4) {
            const float4 xq = *(const float4*)(&xs[lane * XSTR + t4 * 4]);
#pragma unroll
            for (int u = 0; u < 4; ++u) {
                const int tt = t4 * 4 + u;
                const float xu = (u == 0) ? xq.x : (u == 1) ? xq.y : (u == 2) ? xq.z : xq.w;

                // reads of h1(t-1) (before this step's write)
                const float4 qa = *(const float4*)(&h1buf[0]);
                const float4 qb = *(const float4*)(&h1buf[4]);
                const float4 qc = *(const float4*)(&h1buf[8]);
                const float4 qd = *(const float4*)(&h1buf[12]);
                const float4 rqv = *(const float4*)(&h1buf[s2v * 4]);

                // ======== LSTM2 for step t-1 (lagged; fills LSTM1's LDS latency) ========
                {
                    const float2 r01 = make_float2(fmaxf(rqv.x, 0.f), fmaxf(rqv.y, 0.f));
                    const float2 r23 = make_float2(fmaxf(rqv.z, 0.f), fmaxf(rqv.w, 0.f));
                    float2 a2 = make_float2(bias2l, w2h * h2s);
                    a2 = pkfma(w2a, r01, a2);
                    a2 = pkfma(w2b, r23, a2);
                    float p2 = a2.x + a2.y;
                    p2 += DPPF(p2, 0xB1);   // quad_perm [1,0,3,2]  (xor 1)
                    p2 += DPPF(p2, 0x4E);   // quad_perm [2,3,0,1]  (xor 2)
                    const float act2 = fmaf(aA2,
                        __builtin_amdgcn_rcpf(1.0f + __builtin_amdgcn_exp2f(-p2)), aB2);
                    const float fv2 = SWZF(act2, 0x101F);   // xor 4  -> f
                    const float gv2 = SWZF(act2, 0x201F);   // xor 8  -> g
                    const float ov2 = SWZF(act2, 0x301F);   // xor 12 -> o
                    const float c2n = fmaf(fv2, c2, act2 * gv2);   // valid on T2==0
                    const float ec2 = __builtin_amdgcn_exp2f(-2.0f * LOG2E * c2n);
                    const float h2n = ov2 * fmaf(2.0f, __builtin_amdgcn_rcpf(1.0f + ec2), -1.0f);
                    if ((c | tt) != 0) { c2 = c2n; h2 = h2n; }
                    h2s = __shfl(h2, (lane & 3) << 4);      // h2[s] for next step
                }

                // ======== LSTM1 for step t ========
                float2 acc01 = make_float2(xu, 0.f);
                float2 acc23 = make_float2(0.f, 0.f);
                acc01 = pkfma(whh[0], make_float2(qa.x, qa.y), acc01);
                acc23 = pkfma(whh[1], make_float2(qa.z, qa.w), acc23);
                acc01 = pkfma(whh[2], make_float2(qb.x, qb.y), acc01);
                acc23 = pkfma(whh[3], make_float2(qb.z, qb.w), acc23);
                acc01 = pkfma(whh[4], make_float2(qc.x, qc.y), acc01);
                acc23 = pkfma(whh[5], make_float2(qc.z, qc.w), acc23);
                acc01 = pkfma(whh[6], make_float2(qd.x, qd.y), acc01);
                acc23 = pkfma(whh[7], make_float2(qd.z, qd.w), acc23);
                const float pre = (acc01.x + acc23.x) + (acc01.y + acc23.y);

                const float e1 = __builtin_amdgcn_exp2f(-pre);
                const float sg = __builtin_amdgcn_rcpf(1.0f + e1);
                const float act = fmaf(aA1, sg, aB1);
                const float iv = DPPF(act, 0x00);   // quad bcast slot 0 = i
                const float fv = DPPF(act, 0x55);   // slot 1 = f
                const float gv = DPPF(act, 0xAA);   // slot 2 = g
                const float ov = DPPF(act, 0xFF);   // slot 3 = o
                c1 = fmaf(fv, c1, iv * gv);                        // replicated per quad
                const float ec = __builtin_amdgcn_exp2f(-2.0f * LOG2E * c1);
                h1 = ov * fmaf(2.0f, __builtin_amdgcn_rcpf(1.0f + ec), -1.0f);
                if ((lane & 3) == 0) h1buf[j1] = h1;
            }
        }
    }

    // ---- drain: LSTM2 for t = 511 ----
    {
        const float4 rqv = *(const float4*)(&h1buf[s2v * 4]);
        const float2 r01 = make_float2(fmaxf(rqv.x, 0.f), fmaxf(rqv.y, 0.f));
        const float2 r23 = make_float2(fmaxf(rqv.z, 0.f), fmaxf(rqv.w, 0.f));
        float2 a2 = make_float2(bias2l, w2h * h2s);
        a2 = pkfma(w2a, r01, a2);
        a2 = pkfma(w2b, r23, a2);
        float p2 = a2.x + a2.y;
        p2 += DPPF(p2, 0xB1);
        p2 += DPPF(p2, 0x4E);
        const float act2 = fmaf(aA2,
            __builtin_amdgcn_rcpf(1.0f + __builtin_amdgcn_exp2f(-p2)), aB2);
        const float fv2 = SWZF(act2, 0x101F);
        const float gv2 = SWZF(act2, 0x201F);
        const float ov2 = SWZF(act2, 0x301F);
        c2 = fmaf(fv2, c2, act2 * gv2);
        const float ec2 = __builtin_amdgcn_exp2f(-2.0f * LOG2E * c2);
        h2 = ov2 * fmaf(2.0f, __builtin_amdgcn_rcpf(1.0f + ec2), -1.0f);
    }

    // ---- FC + sigmoid: h2[m] lives on lanes 16m (T2==0, s=0) ----
    const float hq0 = __shfl(h2, 0);
    const float hq1 = __shfl(h2, 16);
    const float hq2 = __shfl(h2, 32);
    const float hq3 = __shfl(h2, 48);
    float accf = bfcv;
    accf = fmaf(wfc.x, hq0, accf);
    accf = fmaf(wfc.y, hq1, accf);
    accf = fmaf(wfc.z, hq2, accf);
    accf = fmaf(wfc.w, hq3, accf);
    out[b * 64 + lane] = fsigm(accf);
}

extern "C" void kernel_launch(void* const* d_in, const int* in_sizes, int n_in,
                              void* d_out, int out_size, void* d_ws, size_t ws_size,
                              hipStream_t stream) {
    const float* x    = (const float*)d_in[0];
    const float* Wih1 = (const float*)d_in[1];
    const float* Whh1 = (const float*)d_in[2];
    const float* bih1 = (const float*)d_in[3];
    const float* bhh1 = (const float*)d_in[4];
    const float* Wih2 = (const float*)d_in[5];
    const float* Whh2 = (const float*)d_in[6];
    const float* bih2 = (const float*)d_in[7];
    const float* bhh2 = (const float*)d_in[8];
    const float* Wfc  = (const float*)d_in[9];
    const float* bfc  = (const float*)d_in[10];
    float* out = (float*)d_out;

    lstm_fused_v4<<<dim3(2048), dim3(64), 0, stream>>>(
        x, Wih1, Whh1, bih1, bhh1, Wih2, Whh2, bih2, bhh2, Wfc, bfc, out);
}

// Round 5
// 171.565 us; speedup vs baseline: 3.0538x; 1.0846x over previous
//
#include <hip/hip_runtime.h>
#include <hip/hip_bf16.h>

#define T_ALL 512
#define TB 16
#define NB (T_ALL / TB)
#define LOG2E 1.44269504088896f

typedef __attribute__((ext_vector_type(8))) short bf16x8;
typedef __attribute__((ext_vector_type(4))) float f32x4;

// DPP quad ops / swizzle / bpermute helpers (compile-time patterns)
#define DPPF(v, CTRL) __uint_as_float((unsigned)__builtin_amdgcn_update_dpp(0, (int)__float_as_uint(v), (CTRL), 0xF, 0xF, true))
#define SWZF(v, PAT)  __uint_as_float((unsigned)__builtin_amdgcn_ds_swizzle((int)__float_as_uint(v), (PAT)))
#define BPERM(a, v)   __uint_as_float((unsigned)__builtin_amdgcn_ds_bpermute((a), (int)__float_as_uint(v)))

__device__ __forceinline__ unsigned pack2bf16(float a, float b) {
    unsigned ua = __float_as_uint(a), ub = __float_as_uint(b);
    ua += 0x7FFFu + ((ua >> 16) & 1u);   // RNE
    ub += 0x7FFFu + ((ub >> 16) & 1u);
    return (ua >> 16) | (ub & 0xFFFF0000u);
}
__device__ __forceinline__ bf16x8 make_frag(float4 lo, float4 hi) {
    union { unsigned u[4]; bf16x8 v; } r;
    r.u[0] = pack2bf16(lo.x, lo.y);
    r.u[1] = pack2bf16(lo.z, lo.w);
    r.u[2] = pack2bf16(hi.x, hi.y);
    r.u[3] = pack2bf16(hi.z, hi.w);
    return r.v;
}
__device__ __forceinline__ float4 scale4(float4 v, float s) {
    return make_float4(v.x * s, v.y * s, v.z * s, v.w * s);
}
__device__ __forceinline__ float2 pkfma(float2 a, float2 b, float2 c) {
    return make_float2(fmaf(a.x, b.x, c.x), fmaf(a.y, b.y, c.y));
}
__device__ __forceinline__ float fsigm(float x) {
    return __builtin_amdgcn_rcpf(1.0f + __builtin_amdgcn_exp2f(-LOG2E * x));
}

// One wave per batch row. No LDS for recurrent state:
//  - LSTM1: lane = 4*j + T. Lane computes k-slice s=T partials for all 4 gates
//    of quad j; weight rows pre-permuted [T, T^2, T^1, T^3] so the quad
//    butterfly (2 DPP xor-adds) lands gate T's full sum on lane T, no cndmask.
//    h1 slice h[4T..4T+3] gathered via 4 hoisted-addr ds_bpermute from the
//    (quad-replicated) h1 registers.
//  - LSTM2 (lagged 1 step): lane = 16*m + 4*T2 + s, s = lane&3 = T -> shares
//    the same gathered slice (relu'd). Quad DPP allreduce + 3 ds_swizzle.
// xg (input-gate preacts, pre-scaled) via MFMA into linear LDS, 1 b32/step.
__global__ __launch_bounds__(64, 2)
void lstm_fused_v5(const float* __restrict__ x,
        const float* __restrict__ Wih1, const float* __restrict__ Whh1,
        const float* __restrict__ bih1, const float* __restrict__ bhh1,
        const float* __restrict__ Wih2, const float* __restrict__ Whh2,
        const float* __restrict__ bih2, const float* __restrict__ bhh2,
        const float* __restrict__ Wfc,  const float* __restrict__ bfc,
        float* __restrict__ out)
{
    __shared__ __align__(16) float xg[TB * 64];

    const int lane = threadIdx.x;
    const int tl = lane & 15;     // MFMA: A row / C col
    const int kh = lane >> 4;     // MFMA: k-group
    const size_t b = blockIdx.x;

    const int T1 = lane & 3;      // LSTM1 gate type AND k-slice
    const int j1 = lane >> 2;     // LSTM1 h index
    const int m2 = lane >> 4;     // LSTM2 h index
    const int T2 = (lane >> 2) & 3;  // LSTM2 gate type (slice = T1)

    const float aA1 = (T1 == 2) ? 2.0f : 1.0f, aB1 = (T1 == 2) ? -1.0f : 0.0f;
    const float aA2 = (T2 == 2) ? 2.0f : 1.0f, aB2 = (T2 == 2) ? -1.0f : 0.0f;
    const float sc2 = (T2 == 2) ? 2.0f * LOG2E : LOG2E;

    // ---- B fragments for xg MFMA: Wih1^T, pre-scaled per gate block ----
    bf16x8 wb[4][2];
    float bias1[4];
#pragma unroll
    for (int n = 0; n < 4; ++n) {
        const float scn = (n == 2) ? 2.0f * LOG2E : LOG2E;
#pragma unroll
        for (int kk = 0; kk < 2; ++kk) {
            const float* wp = Wih1 + (size_t)(n * 16 + tl) * 64 + kk * 32 + kh * 8;
            wb[n][kk] = make_frag(scale4(*(const float4*)wp, scn),
                                  scale4(*(const float4*)(wp + 4), scn));
        }
        bias1[n] = (bih1[n * 16 + tl] + bhh1[n * 16 + tl]) * scn;
    }

    // ---- LSTM1 butterfly weights: rows [T, T^2, T^1, T^3], k-slice 4*T1.. ----
    float2 wq01[4], wq23[4];
    {
        const float sA = (T1 == 2) ? 2.0f * LOG2E : LOG2E;
        const float sB = ((T1 ^ 2) == 2) ? 2.0f * LOG2E : LOG2E;
        const float sC = ((T1 ^ 1) == 2) ? 2.0f * LOG2E : LOG2E;
        const float sD = ((T1 ^ 3) == 2) ? 2.0f * LOG2E : LOG2E;
        const float4 wa = scale4(*(const float4*)(Whh1 + (T1 * 16 + j1) * 16 + 4 * T1), sA);
        const float4 wbv = scale4(*(const float4*)(Whh1 + ((T1 ^ 2) * 16 + j1) * 16 + 4 * T1), sB);
        const float4 wc = scale4(*(const float4*)(Whh1 + ((T1 ^ 1) * 16 + j1) * 16 + 4 * T1), sC);
        const float4 wd = scale4(*(const float4*)(Whh1 + ((T1 ^ 3) * 16 + j1) * 16 + 4 * T1), sD);
        wq01[0] = make_float2(wa.x, wbv.x); wq23[0] = make_float2(wc.x, wd.x);
        wq01[1] = make_float2(wa.y, wbv.y); wq23[1] = make_float2(wc.y, wd.y);
        wq01[2] = make_float2(wa.z, wbv.z); wq23[2] = make_float2(wc.z, wd.z);
        wq01[3] = make_float2(wa.w, wbv.w); wq23[3] = make_float2(wc.w, wd.w);
    }

    // ---- LSTM2 weights: gate (m2,T2), k-slice 4*T1..+3 ----
    const int row2 = T2 * 4 + m2;
    const float4 w2q = scale4(*(const float4*)(Wih2 + row2 * 16 + 4 * T1), sc2);
    const float2 w2a = make_float2(w2q.x, w2q.y);
    const float2 w2b = make_float2(w2q.z, w2q.w);
    const float w2h = Whh2[row2 * 4 + T1] * sc2;
    const float bias2l = (T1 == 0) ? (bih2[row2] + bhh2[row2]) * sc2 : 0.0f;

    const float4 wfc = *(const float4*)(Wfc + lane * 4);
    const float bfcv = bfc[lane];

    // ---- hoisted cross-lane addresses (bytes) ----
    int ga[4];
#pragma unroll
    for (int u = 0; u < 4; ++u)
        ga[u] = (16 * T1 + 4 * u + kh) << 2;   // src lane for h[4*T1+u] (replica kh)
    const int ha2 = T1 << 6;                    // src lane 16*T1 for h2[T1]
    const int xoff = (T1 * 16 + j1) << 2;       // this lane's gate column in xg

    float c1 = 0.f, h1 = 0.f, c2 = 0.f, h2v = 0.f, h2s = 0.f;
    float g0 = 0.f, g1 = 0.f, g2 = 0.f, g3 = 0.f;   // gathered h1(t-1) slice

    const float* xb = x + b * (size_t)(T_ALL * 64);

    // ---- prefetch x block 0 ----
    float4 xpf[4];
#pragma unroll
    for (int kk = 0; kk < 2; ++kk)
#pragma unroll
        for (int hf = 0; hf < 2; ++hf)
            xpf[kk * 2 + hf] = *(const float4*)(xb + tl * 64 + kk * 32 + kh * 8 + hf * 4);

    for (int c = 0; c < NB; ++c) {
        bf16x8 a0 = make_frag(xpf[0], xpf[1]);
        bf16x8 a1 = make_frag(xpf[2], xpf[3]);
        if (c + 1 < NB) {
            const float* src = xb + (size_t)(c + 1) * (TB * 64);
#pragma unroll
            for (int kk = 0; kk < 2; ++kk)
#pragma unroll
                for (int hf = 0; hf < 2; ++hf)
                    xpf[kk * 2 + hf] = *(const float4*)(src + tl * 64 + kk * 32 + kh * 8 + hf * 4);
        }

        // xg[t*64 + g] (linear, conflict-free reads) via 8 MFMAs
#pragma unroll
        for (int n = 0; n < 4; ++n) {
            f32x4 acc = {bias1[n], bias1[n], bias1[n], bias1[n]};
            acc = __builtin_amdgcn_mfma_f32_16x16x32_bf16(a0, wb[n][0], acc, 0, 0, 0);
            acc = __builtin_amdgcn_mfma_f32_16x16x32_bf16(a1, wb[n][1], acc, 0, 0, 0);
#pragma unroll
            for (int r = 0; r < 4; ++r)
                xg[(kh * 4 + r) * 64 + n * 16 + tl] = acc[r];
        }

        // ---- sequential scan over 16 timesteps ----
#pragma unroll
        for (int tt = 0; tt < TB; ++tt) {
            const float xu = *(const float*)((const char*)xg + (tt * 256) + xoff);

            // ======== LSTM2 for step t-1 (lagged; independent chain) ========
            {
                const float r0 = fmaxf(g0, 0.f), r1 = fmaxf(g1, 0.f);
                const float r2 = fmaxf(g2, 0.f), r3 = fmaxf(g3, 0.f);
                float2 a2 = make_float2(bias2l, w2h * h2s);
                a2 = pkfma(w2a, make_float2(r0, r1), a2);
                a2 = pkfma(w2b, make_float2(r2, r3), a2);
                float p2 = a2.x + a2.y;
                p2 += DPPF(p2, 0xB1);   // quad allreduce over k-slices
                p2 += DPPF(p2, 0x4E);
                const float act2 = fmaf(aA2,
                    __builtin_amdgcn_rcpf(1.0f + __builtin_amdgcn_exp2f(-p2)), aB2);
                const float fv2 = SWZF(act2, 0x101F);   // xor 4  -> f
                const float gv2 = SWZF(act2, 0x201F);   // xor 8  -> g
                const float ov2 = SWZF(act2, 0x301F);   // xor 12 -> o
                const float c2n = fmaf(fv2, c2, act2 * gv2);     // valid on T2==0
                const float ec2 = __builtin_amdgcn_exp2f(-2.0f * LOG2E * c2n);
                const float h2n = ov2 * fmaf(2.0f, __builtin_amdgcn_rcpf(1.0f + ec2), -1.0f);
                if ((c | tt) != 0) { c2 = c2n; h2v = h2n; }
                h2s = BPERM(ha2, h2v);
            }

            // ======== LSTM1 for step t ========
            float2 acc01 = make_float2(0.f, 0.f), acc23 = make_float2(0.f, 0.f);
            acc01 = pkfma(wq01[0], make_float2(g0, g0), acc01);
            acc23 = pkfma(wq23[0], make_float2(g0, g0), acc23);
            acc01 = pkfma(wq01[1], make_float2(g1, g1), acc01);
            acc23 = pkfma(wq23[1], make_float2(g1, g1), acc23);
            acc01 = pkfma(wq01[2], make_float2(g2, g2), acc01);
            acc23 = pkfma(wq23[2], make_float2(g2, g2), acc23);
            acc01 = pkfma(wq01[3], make_float2(g3, g3), acc01);
            acc23 = pkfma(wq23[3], make_float2(g3, g3), acc23);
            // butterfly: round1 xor1, round2 xor2 (rows pre-permuted, no cndmask)
            const float q0 = acc01.x + DPPF(acc23.x, 0xB1);
            const float q1 = acc01.y + DPPF(acc23.y, 0xB1);
            const float pre = q0 + DPPF(q1, 0x4E) + xu;

            const float act = fmaf(aA1,
                __builtin_amdgcn_rcpf(1.0f + __builtin_amdgcn_exp2f(-pre)), aB1);
            const float iv = DPPF(act, 0x00);   // quad slot 0 = i
            const float fv = DPPF(act, 0x55);   // slot 1 = f
            const float gv = DPPF(act, 0xAA);   // slot 2 = g
            const float ov = DPPF(act, 0xFF);   // slot 3 = o
            c1 = fmaf(fv, c1, iv * gv);                        // replicated per quad
            const float ec = __builtin_amdgcn_exp2f(-2.0f * LOG2E * c1);
            h1 = ov * fmaf(2.0f, __builtin_amdgcn_rcpf(1.0f + ec), -1.0f);

            // gather h1 slice for next step (feeds BOTH layers)
            g0 = BPERM(ga[0], h1);
            g1 = BPERM(ga[1], h1);
            g2 = BPERM(ga[2], h1);
            g3 = BPERM(ga[3], h1);
        }
    }

    // ---- drain: LSTM2 for t = 511 ----
    {
        const float r0 = fmaxf(g0, 0.f), r1 = fmaxf(g1, 0.f);
        const float r2 = fmaxf(g2, 0.f), r3 = fmaxf(g3, 0.f);
        float2 a2 = make_float2(bias2l, w2h * h2s);
        a2 = pkfma(w2a, make_float2(r0, r1), a2);
        a2 = pkfma(w2b, make_float2(r2, r3), a2);
        float p2 = a2.x + a2.y;
        p2 += DPPF(p2, 0xB1);
        p2 += DPPF(p2, 0x4E);
        const float act2 = fmaf(aA2,
            __builtin_amdgcn_rcpf(1.0f + __builtin_amdgcn_exp2f(-p2)), aB2);
        const float fv2 = SWZF(act2, 0x101F);
        const float gv2 = SWZF(act2, 0x201F);
        const float ov2 = SWZF(act2, 0x301F);
        c2 = fmaf(fv2, c2, act2 * gv2);
        const float ec2 = __builtin_amdgcn_exp2f(-2.0f * LOG2E * c2);
        h2v = ov2 * fmaf(2.0f, __builtin_amdgcn_rcpf(1.0f + ec2), -1.0f);
    }

    // ---- FC + sigmoid: h2[m] valid on lanes 16m (T2==0) ----
    const float hq0 = __shfl(h2v, 0);
    const float hq1 = __shfl(h2v, 16);
    const float hq2 = __shfl(h2v, 32);
    const float hq3 = __shfl(h2v, 48);
    float accf = bfcv;
    accf = fmaf(wfc.x, hq0, accf);
    accf = fmaf(wfc.y, hq1, accf);
    accf = fmaf(wfc.z, hq2, accf);
    accf = fmaf(wfc.w, hq3, accf);
    out[b * 64 + lane] = fsigm(accf);
}

extern "C" void kernel_launch(void* const* d_in, const int* in_sizes, int n_in,
                              void* d_out, int out_size, void* d_ws, size_t ws_size,
                              hipStream_t stream) {
    const float* x    = (const float*)d_in[0];
    const float* Wih1 = (const float*)d_in[1];
    const float* Whh1 = (const float*)d_in[2];
    const float* bih1 = (const float*)d_in[3];
    const float* bhh1 = (const float*)d_in[4];
    const float* Wih2 = (const float*)d_in[5];
    const float* Whh2 = (const float*)d_in[6];
    const float* bih2 = (const float*)d_in[7];
    const float* bhh2 = (const float*)d_in[8];
    const float* Wfc  = (const float*)d_in[9];
    const float* bfc  = (const float*)d_in[10];
    float* out = (float*)d_out;

    lstm_fused_v5<<<dim3(2048), dim3(64), 0, stream>>>(
        x, Wih1, Whh1, bih1, bhh1, Wih2, Whh2, bih2, bhh2, Wfc, bfc, out);
}